// Round 1
// baseline (554.688 us; speedup 1.0000x reference)
//
#include <hip/hip_runtime.h>

#define NNODES 50000
#define NREL   90
#define NEDGE  800000
#define HDIM   16
#define NBASIS 30
#define NCLS   8

// ---------------- degree: deg[dst*R + rel] += 1 ----------------
__global__ __launch_bounds__(256) void deg_kernel(const int* __restrict__ ei,
                                                  const int* __restrict__ et,
                                                  float* __restrict__ deg) {
    int e = blockIdx.x * blockDim.x + threadIdx.x;
    if (e >= NEDGE) return;
    int dst = ei[NEDGE + e];
    int r   = et[e];
    atomicAdd(&deg[dst * NREL + r], 1.0f);
}

// ---------------- layer 1: h[dst,h] += norm * sum_b comp1[r,b]*basis1[b,src,h] ----------------
// one thread per (edge, h); 16 lanes of an edge read 64B contiguous per b
__global__ __launch_bounds__(256) void layer1_kernel(const int* __restrict__ ei,
                                                     const int* __restrict__ et,
                                                     const float* __restrict__ basis1,
                                                     const float* __restrict__ comp1,
                                                     const float* __restrict__ deg,
                                                     float* __restrict__ h) {
    int idx = blockIdx.x * blockDim.x + threadIdx.x;
    if (idx >= NEDGE * HDIM) return;
    int e  = idx >> 4;
    int hh = idx & (HDIM - 1);
    int src = ei[e];
    int dst = ei[NEDGE + e];
    int r   = et[e];
    float d = deg[dst * NREL + r];
    float norm = (d > 0.f) ? (1.0f / d) : 0.f;   // d>=1 in practice (edge counts itself)
    const float* __restrict__ cp = comp1 + r * NBASIS;
    float acc = 0.f;
#pragma unroll
    for (int b = 0; b < NBASIS; ++b) {
        acc += cp[b] * basis1[(b * NNODES + src) * HDIM + hh];
    }
    atomicAdd(&h[dst * HDIM + hh], norm * acc);
}

// ---------------- h = relu(h + root1 + bias1) ----------------
__global__ __launch_bounds__(256) void relu_kernel(float* __restrict__ h,
                                                   const float* __restrict__ root1,
                                                   const float* __restrict__ bias1) {
    int i = blockIdx.x * blockDim.x + threadIdx.x;
    if (i >= NNODES * HDIM) return;
    float v = h[i] + root1[i] + bias1[i & (HDIM - 1)];
    h[i] = v > 0.f ? v : 0.f;
}

// ---------------- W2[r,h,c] = sum_b comp2[r,b]*basis2[b,h,c] ----------------
__global__ __launch_bounds__(256) void w2_kernel(const float* __restrict__ basis2,
                                                 const float* __restrict__ comp2,
                                                 float* __restrict__ W2) {
    int i = blockIdx.x * blockDim.x + threadIdx.x;
    if (i >= NREL * HDIM * NCLS) return;
    int c  = i & (NCLS - 1);
    int hh = (i >> 3) & (HDIM - 1);
    int r  = i >> 7;  // H*C = 128
    float acc = 0.f;
#pragma unroll
    for (int b = 0; b < NBASIS; ++b)
        acc += comp2[r * NBASIS + b] * basis2[(b * HDIM + hh) * NCLS + c];
    W2[i] = acc;
}

// ---------------- layer 2 messages: out_tmp[dst,c] += norm * sum_h h[src,h]*W2[r,h,c] ----------------
__global__ __launch_bounds__(256) void layer2_kernel(const int* __restrict__ ei,
                                                     const int* __restrict__ et,
                                                     const float* __restrict__ h,
                                                     const float* __restrict__ W2,
                                                     const float* __restrict__ deg,
                                                     float* __restrict__ out_tmp) {
    int idx = blockIdx.x * blockDim.x + threadIdx.x;
    if (idx >= NEDGE * NCLS) return;
    int e = idx >> 3;
    int c = idx & (NCLS - 1);
    int src = ei[e];
    int dst = ei[NEDGE + e];
    int r   = et[e];
    float d = deg[dst * NREL + r];
    float norm = (d > 0.f) ? (1.0f / d) : 0.f;
    const float* __restrict__ w = W2 + r * HDIM * NCLS + c;
    const float* __restrict__ hv = h + src * HDIM;
    float acc = 0.f;
#pragma unroll
    for (int hh = 0; hh < HDIM; ++hh)
        acc += hv[hh] * w[hh * NCLS];
    atomicAdd(&out_tmp[dst * NCLS + c], norm * acc);
}

// ---------------- epilogue: out = log_softmax(out_tmp + h @ root2 + bias2) ----------------
__global__ __launch_bounds__(256) void final_kernel(const float* __restrict__ out_tmp,
                                                    const float* __restrict__ h,
                                                    const float* __restrict__ root2,
                                                    const float* __restrict__ bias2,
                                                    float* __restrict__ out) {
    int n = blockIdx.x * blockDim.x + threadIdx.x;
    if (n >= NNODES) return;
    float hv[HDIM];
#pragma unroll
    for (int i = 0; i < HDIM; ++i) hv[i] = h[n * HDIM + i];
    float v[NCLS];
    float mx = -1e30f;
#pragma unroll
    for (int c = 0; c < NCLS; ++c) {
        float acc = out_tmp[n * NCLS + c] + bias2[c];
#pragma unroll
        for (int i = 0; i < HDIM; ++i) acc += hv[i] * root2[i * NCLS + c];
        v[c] = acc;
        mx = fmaxf(mx, acc);
    }
    float s = 0.f;
#pragma unroll
    for (int c = 0; c < NCLS; ++c) s += expf(v[c] - mx);
    float ls = logf(s);
#pragma unroll
    for (int c = 0; c < NCLS; ++c) out[n * NCLS + c] = v[c] - mx - ls;
}

extern "C" void kernel_launch(void* const* d_in, const int* in_sizes, int n_in,
                              void* d_out, int out_size, void* d_ws, size_t ws_size,
                              hipStream_t stream) {
    const int*   ei     = (const int*)d_in[0];     // (2, E)
    const int*   et     = (const int*)d_in[1];     // (E,)
    const float* basis1 = (const float*)d_in[2];   // (B, N, H)
    const float* comp1  = (const float*)d_in[3];   // (R, B)
    const float* root1  = (const float*)d_in[4];   // (N, H)
    const float* bias1  = (const float*)d_in[5];   // (H,)
    const float* basis2 = (const float*)d_in[6];   // (B, H, C)
    const float* comp2  = (const float*)d_in[7];   // (R, B)
    const float* root2  = (const float*)d_in[8];   // (H, C)
    const float* bias2  = (const float*)d_in[9];   // (C,)
    float* out = (float*)d_out;

    float* ws      = (float*)d_ws;
    float* deg     = ws;                                   // N*R      = 4,500,000
    float* h       = deg + (size_t)NNODES * NREL;          // N*H      =   800,000
    float* W2      = h + (size_t)NNODES * HDIM;            // R*H*C    =    11,520
    float* out_tmp = W2 + (size_t)NREL * HDIM * NCLS;      // N*C      =   400,000

    size_t total_ws_floats = (size_t)NNODES * NREL + (size_t)NNODES * HDIM +
                             (size_t)NREL * HDIM * NCLS + (size_t)NNODES * NCLS;
    hipMemsetAsync(d_ws, 0, total_ws_floats * sizeof(float), stream);

    deg_kernel<<<(NEDGE + 255) / 256, 256, 0, stream>>>(ei, et, deg);
    layer1_kernel<<<(NEDGE * HDIM + 255) / 256, 256, 0, stream>>>(ei, et, basis1, comp1, deg, h);
    relu_kernel<<<(NNODES * HDIM + 255) / 256, 256, 0, stream>>>(h, root1, bias1);
    w2_kernel<<<(NREL * HDIM * NCLS + 255) / 256, 256, 0, stream>>>(basis2, comp2, W2);
    layer2_kernel<<<(NEDGE * NCLS + 255) / 256, 256, 0, stream>>>(ei, et, h, W2, deg, out_tmp);
    final_kernel<<<(NNODES + 255) / 256, 256, 0, stream>>>(out_tmp, h, root2, bias2, out);
}

// Round 2
// 271.146 us; speedup vs baseline: 2.0457x; 2.0457x over previous
//
#include <hip/hip_runtime.h>

#define NNODES 50000
#define NREL   90
#define NEDGE  800000
#define HDIM   16
#define NBASIS 30
#define NCLS   8
#define SCAN_B 256
#define NB1    ((NNODES + SCAN_B - 1) / SCAN_B)   // 196

// ============================================================
// counting-sort pipeline: bucket edges by src
// ============================================================

// deg[dst*R+r] += 1 ; cnt[src] += 1
__global__ __launch_bounds__(256) void degcnt_kernel(const int* __restrict__ ei,
                                                     const int* __restrict__ et,
                                                     int* __restrict__ deg,
                                                     int* __restrict__ cnt) {
    int e = blockIdx.x * blockDim.x + threadIdx.x;
    if (e >= NEDGE) return;
    int src = ei[e];
    int dst = ei[NEDGE + e];
    int r   = et[e];
    atomicAdd(&deg[dst * NREL + r], 1);
    atomicAdd(&cnt[src], 1);
}

// per-block exclusive scan of cnt -> offs(local), block totals -> bsum
__global__ __launch_bounds__(SCAN_B) void scan1_kernel(const int* __restrict__ cnt,
                                                       int* __restrict__ offs,
                                                       int* __restrict__ bsum) {
    __shared__ int tmp[SCAN_B];
    int gid = blockIdx.x * SCAN_B + threadIdx.x;
    int v = (gid < NNODES) ? cnt[gid] : 0;
    tmp[threadIdx.x] = v;
    for (int d = 1; d < SCAN_B; d <<= 1) {
        __syncthreads();
        int t = (threadIdx.x >= d) ? tmp[threadIdx.x - d] : 0;
        __syncthreads();
        tmp[threadIdx.x] += t;
    }
    __syncthreads();
    if (gid < NNODES) offs[gid] = tmp[threadIdx.x] - v;   // exclusive within block
    if (threadIdx.x == SCAN_B - 1) bsum[blockIdx.x] = tmp[SCAN_B - 1];
}

// scan the NB1 block sums (single block)
__global__ __launch_bounds__(SCAN_B) void scan2_kernel(const int* __restrict__ bsum,
                                                       int* __restrict__ bpre) {
    __shared__ int tmp[SCAN_B];
    int v = (threadIdx.x < NB1) ? bsum[threadIdx.x] : 0;
    tmp[threadIdx.x] = v;
    for (int d = 1; d < SCAN_B; d <<= 1) {
        __syncthreads();
        int t = (threadIdx.x >= d) ? tmp[threadIdx.x - d] : 0;
        __syncthreads();
        tmp[threadIdx.x] += t;
    }
    __syncthreads();
    if (threadIdx.x < NB1) bpre[threadIdx.x] = tmp[threadIdx.x] - v;
}

// offs += block prefix ; cursor = offs
__global__ __launch_bounds__(SCAN_B) void scanadd_kernel(int* __restrict__ offs,
                                                         const int* __restrict__ bpre,
                                                         int* __restrict__ cursor) {
    int i = blockIdx.x * SCAN_B + threadIdx.x;
    if (i >= NNODES) return;
    int v = offs[i] + bpre[i >> 8];
    offs[i] = v;
    cursor[i] = v;
}

// scatter edges into src buckets, packing (dst, rel, norm)
__global__ __launch_bounds__(256) void scatter_kernel(const int* __restrict__ ei,
                                                      const int* __restrict__ et,
                                                      const int* __restrict__ deg,
                                                      int* __restrict__ cursor,
                                                      int* __restrict__ s_dst,
                                                      int* __restrict__ s_rel,
                                                      float* __restrict__ s_norm) {
    int e = blockIdx.x * blockDim.x + threadIdx.x;
    if (e >= NEDGE) return;
    int src = ei[e];
    int dst = ei[NEDGE + e];
    int r   = et[e];
    int pos = atomicAdd(&cursor[src], 1);
    s_dst[pos]  = dst;
    s_rel[pos]  = r;
    s_norm[pos] = 1.0f / (float)deg[dst * NREL + r];   // deg >= 1 for any touched (dst,r)
}

// ============================================================
// layer 1 (bucketed): block = 256 (4 waves), one src per wave.
// Stage basis1[:, src, :] (480 floats) in LDS once, reuse for all edges of src.
// Within a wave: 4 groups x 16 lanes; group = one edge, lane = h channel.
// ============================================================
__global__ __launch_bounds__(256) void layer1b_kernel(const float* __restrict__ basis1,
                                                      const float* __restrict__ comp1,
                                                      const int* __restrict__ offs,
                                                      const int* __restrict__ cnt,
                                                      const int* __restrict__ s_dst,
                                                      const int* __restrict__ s_rel,
                                                      const float* __restrict__ s_norm,
                                                      float* __restrict__ h) {
    __shared__ float bs[4 * NBASIS * HDIM];   // 4 srcs x 480 floats
    int src0 = blockIdx.x * 4;
    int t = threadIdx.x;
    for (int i = t; i < 4 * NBASIS * HDIM; i += 256) {
        int sg  = i / (NBASIS * HDIM);
        int rem = i - sg * (NBASIS * HDIM);
        int b   = rem >> 4;
        int hh  = rem & (HDIM - 1);
        bs[i] = basis1[b * (NNODES * HDIM) + (src0 + sg) * HDIM + hh];
    }
    __syncthreads();
    int wave = t >> 6;
    int lane = t & 63;
    int src  = src0 + wave;
    int n0 = offs[src];
    int n1 = n0 + cnt[src];
    int hh = lane & (HDIM - 1);
    int g  = lane >> 4;
    const float* __restrict__ bw = bs + wave * (NBASIS * HDIM);
    for (int j = n0 + g; j < n1; j += 4) {
        int   dst = s_dst[j];
        int   r   = s_rel[j];
        float nm  = s_norm[j];
        const float* __restrict__ cp = comp1 + r * NBASIS;
        float acc = 0.f;
#pragma unroll
        for (int b = 0; b < NBASIS; ++b)
            acc = fmaf(cp[b], bw[b * HDIM + hh], acc);
        atomicAdd(&h[dst * HDIM + hh], nm * acc);
    }
}

// ---------------- h = relu(h + root1 + bias1) ----------------
__global__ __launch_bounds__(256) void relu_kernel(float* __restrict__ h,
                                                   const float* __restrict__ root1,
                                                   const float* __restrict__ bias1) {
    int i = blockIdx.x * blockDim.x + threadIdx.x;
    if (i >= NNODES * HDIM) return;
    float v = h[i] + root1[i] + bias1[i & (HDIM - 1)];
    h[i] = v > 0.f ? v : 0.f;
}

// ---------------- W2[r,h,c] = sum_b comp2[r,b]*basis2[b,h,c] ----------------
__global__ __launch_bounds__(256) void w2_kernel(const float* __restrict__ basis2,
                                                 const float* __restrict__ comp2,
                                                 float* __restrict__ W2) {
    int i = blockIdx.x * blockDim.x + threadIdx.x;
    if (i >= NREL * HDIM * NCLS) return;
    int c  = i & (NCLS - 1);
    int hh = (i >> 3) & (HDIM - 1);
    int r  = i >> 7;  // H*C = 128
    float acc = 0.f;
#pragma unroll
    for (int b = 0; b < NBASIS; ++b)
        acc += comp2[r * NBASIS + b] * basis2[(b * HDIM + hh) * NCLS + c];
    W2[i] = acc;
}

// ============================================================
// layer 2 (bucketed): block = 256 (4 waves), one src per wave.
// Stage h[src] (16 floats) once; 8 groups x 8 lanes, group = edge, lane = class.
// ============================================================
__global__ __launch_bounds__(256) void layer2b_kernel(const float* __restrict__ h,
                                                      const float* __restrict__ W2,
                                                      const int* __restrict__ offs,
                                                      const int* __restrict__ cnt,
                                                      const int* __restrict__ s_dst,
                                                      const int* __restrict__ s_rel,
                                                      const float* __restrict__ s_norm,
                                                      float* __restrict__ out_tmp) {
    __shared__ float hv[4 * HDIM];
    int src0 = blockIdx.x * 4;
    int t = threadIdx.x;
    if (t < 4 * HDIM) hv[t] = h[src0 * HDIM + t];   // contiguous 64 floats
    __syncthreads();
    int wave = t >> 6;
    int lane = t & 63;
    int src  = src0 + wave;
    int n0 = offs[src];
    int n1 = n0 + cnt[src];
    int c = lane & (NCLS - 1);
    int g = lane >> 3;
    const float* __restrict__ hw = hv + wave * HDIM;
    for (int j = n0 + g; j < n1; j += 8) {
        int   dst = s_dst[j];
        int   r   = s_rel[j];
        float nm  = s_norm[j];
        const float* __restrict__ w = W2 + r * (HDIM * NCLS) + c;
        float acc = 0.f;
#pragma unroll
        for (int k = 0; k < HDIM; ++k)
            acc = fmaf(hw[k], w[k * NCLS], acc);
        atomicAdd(&out_tmp[dst * NCLS + c], nm * acc);
    }
}

// ---------------- epilogue: out = log_softmax(out_tmp + h @ root2 + bias2) ----------------
__global__ __launch_bounds__(256) void final_kernel(const float* __restrict__ out_tmp,
                                                    const float* __restrict__ h,
                                                    const float* __restrict__ root2,
                                                    const float* __restrict__ bias2,
                                                    float* __restrict__ out) {
    int n = blockIdx.x * blockDim.x + threadIdx.x;
    if (n >= NNODES) return;
    float hv[HDIM];
#pragma unroll
    for (int i = 0; i < HDIM; ++i) hv[i] = h[n * HDIM + i];
    float v[NCLS];
    float mx = -1e30f;
#pragma unroll
    for (int c = 0; c < NCLS; ++c) {
        float acc = out_tmp[n * NCLS + c] + bias2[c];
#pragma unroll
        for (int i = 0; i < HDIM; ++i) acc += hv[i] * root2[i * NCLS + c];
        v[c] = acc;
        mx = fmaxf(mx, acc);
    }
    float s = 0.f;
#pragma unroll
    for (int c = 0; c < NCLS; ++c) s += expf(v[c] - mx);
    float ls = logf(s);
#pragma unroll
    for (int c = 0; c < NCLS; ++c) out[n * NCLS + c] = v[c] - mx - ls;
}

// ============================================================
// fallback (round-1 flat path; needs only 22.85 MB ws)
// ============================================================
__global__ __launch_bounds__(256) void layer1_flat(const int* __restrict__ ei,
                                                   const int* __restrict__ et,
                                                   const float* __restrict__ basis1,
                                                   const float* __restrict__ comp1,
                                                   const int* __restrict__ deg,
                                                   float* __restrict__ h) {
    int idx = blockIdx.x * blockDim.x + threadIdx.x;
    if (idx >= NEDGE * HDIM) return;
    int e  = idx >> 4;
    int hh = idx & (HDIM - 1);
    int src = ei[e];
    int dst = ei[NEDGE + e];
    int r   = et[e];
    float norm = 1.0f / (float)deg[dst * NREL + r];
    const float* __restrict__ cp = comp1 + r * NBASIS;
    float acc = 0.f;
#pragma unroll
    for (int b = 0; b < NBASIS; ++b)
        acc += cp[b] * basis1[(b * NNODES + src) * HDIM + hh];
    atomicAdd(&h[dst * HDIM + hh], norm * acc);
}

__global__ __launch_bounds__(256) void layer2_flat(const int* __restrict__ ei,
                                                   const int* __restrict__ et,
                                                   const float* __restrict__ h,
                                                   const float* __restrict__ W2,
                                                   const int* __restrict__ deg,
                                                   float* __restrict__ out_tmp) {
    int idx = blockIdx.x * blockDim.x + threadIdx.x;
    if (idx >= NEDGE * NCLS) return;
    int e = idx >> 3;
    int c = idx & (NCLS - 1);
    int src = ei[e];
    int dst = ei[NEDGE + e];
    int r   = et[e];
    float norm = 1.0f / (float)deg[dst * NREL + r];
    const float* __restrict__ w = W2 + r * HDIM * NCLS + c;
    const float* __restrict__ hv = h + src * HDIM;
    float acc = 0.f;
#pragma unroll
    for (int hh = 0; hh < HDIM; ++hh)
        acc += hv[hh] * w[hh * NCLS];
    atomicAdd(&out_tmp[dst * NCLS + c], norm * acc);
}

extern "C" void kernel_launch(void* const* d_in, const int* in_sizes, int n_in,
                              void* d_out, int out_size, void* d_ws, size_t ws_size,
                              hipStream_t stream) {
    const int*   ei     = (const int*)d_in[0];     // (2, E)
    const int*   et     = (const int*)d_in[1];     // (E,)
    const float* basis1 = (const float*)d_in[2];   // (B, N, H)
    const float* comp1  = (const float*)d_in[3];   // (R, B)
    const float* root1  = (const float*)d_in[4];   // (N, H)
    const float* bias1  = (const float*)d_in[5];   // (H,)
    const float* basis2 = (const float*)d_in[6];   // (B, H, C)
    const float* comp2  = (const float*)d_in[7];   // (R, B)
    const float* root2  = (const float*)d_in[8];   // (H, C)
    const float* bias2  = (const float*)d_in[9];   // (C,)
    float* out = (float*)d_out;

    // ---- workspace layout (4-byte words) ----
    int*   deg     = (int*)d_ws;                               // N*R
    float* h       = (float*)(deg + (size_t)NNODES * NREL);    // N*H
    float* out_tmp = h + (size_t)NNODES * HDIM;                // N*C
    int*   cnt     = (int*)(out_tmp + (size_t)NNODES * NCLS);  // N
    // zeroed region ends here
    size_t zero_words = (size_t)NNODES * NREL + NNODES * HDIM + NNODES * NCLS + NNODES;
    float* W2      = (float*)(cnt + NNODES);                   // R*H*C
    int*   offs    = (int*)(W2 + (size_t)NREL * HDIM * NCLS);  // N
    int*   cursor  = offs + NNODES;                            // N
    int*   bsum    = cursor + NNODES;                          // NB1
    int*   bpre    = bsum + NB1;                               // NB1
    int*   s_dst   = bpre + NB1;                               // E
    int*   s_rel   = s_dst + NEDGE;                            // E
    float* s_norm  = (float*)(s_rel + NEDGE);                  // E
    size_t total_words = zero_words + (size_t)NREL * HDIM * NCLS + 2 * NNODES + 2 * NB1 +
                         3 * (size_t)NEDGE;

    if (ws_size < total_words * sizeof(float)) {
        // -------- fallback: round-1 flat path (22.85 MB) --------
        hipMemsetAsync(d_ws, 0, zero_words * sizeof(float), stream);
        float* W2f = (float*)(cnt + NNODES);
        degcnt_kernel<<<(NEDGE + 255) / 256, 256, 0, stream>>>(ei, et, deg, cnt);
        layer1_flat<<<(NEDGE * HDIM + 255) / 256, 256, 0, stream>>>(ei, et, basis1, comp1, deg, h);
        relu_kernel<<<(NNODES * HDIM + 255) / 256, 256, 0, stream>>>(h, root1, bias1);
        w2_kernel<<<(NREL * HDIM * NCLS + 255) / 256, 256, 0, stream>>>(basis2, comp2, W2f);
        layer2_flat<<<(NEDGE * NCLS + 255) / 256, 256, 0, stream>>>(ei, et, h, W2f, deg, out_tmp);
        final_kernel<<<(NNODES + 255) / 256, 256, 0, stream>>>(out_tmp, h, root2, bias2, out);
        return;
    }

    hipMemsetAsync(d_ws, 0, zero_words * sizeof(float), stream);

    degcnt_kernel<<<(NEDGE + 255) / 256, 256, 0, stream>>>(ei, et, deg, cnt);
    scan1_kernel<<<NB1, SCAN_B, 0, stream>>>(cnt, offs, bsum);
    scan2_kernel<<<1, SCAN_B, 0, stream>>>(bsum, bpre);
    scanadd_kernel<<<NB1, SCAN_B, 0, stream>>>(offs, bpre, cursor);
    scatter_kernel<<<(NEDGE + 255) / 256, 256, 0, stream>>>(ei, et, deg, cursor, s_dst, s_rel, s_norm);

    layer1b_kernel<<<NNODES / 4, 256, 0, stream>>>(basis1, comp1, offs, cnt, s_dst, s_rel, s_norm, h);
    relu_kernel<<<(NNODES * HDIM + 255) / 256, 256, 0, stream>>>(h, root1, bias1);
    w2_kernel<<<(NREL * HDIM * NCLS + 255) / 256, 256, 0, stream>>>(basis2, comp2, W2);
    layer2b_kernel<<<NNODES / 4, 256, 0, stream>>>(h, W2, offs, cnt, s_dst, s_rel, s_norm, out_tmp);
    final_kernel<<<(NNODES + 255) / 256, 256, 0, stream>>>(out_tmp, h, root2, bias2, out);
}